// Round 8
// baseline (252.559 us; speedup 1.0000x reference)
//
#include <hip/hip_runtime.h>

#define DIM 192
#define YZ (DIM * DIM)          // 36864
#define YZ4 (YZ / 4)            // 9216 float4 per x-slice
#define VOL ((size_t)DIM * YZ)
#define NB 2
#define PADW 4
#define TILE 32
#define TH 40                   // TILE + 2*PADW (y halo rows)
#define SZP 36                  // Szx row stride (floats): quads 16B-aligned, bank-stride 4
#define SZ_CH (TH * SZP)        // 1440
#define SZ_SZ (5 * SZ_CH)       // 7200 floats = 28.8 KB -> 5 blocks/CU
#define XCH 12                  // x-chunk per block -> 16 chunks
#define NCHUNK (DIM / XCH)      // 16

__device__ inline float4 f4add(float4 a, float4 b) { return make_float4(a.x+b.x, a.y+b.y, a.z+b.z, a.w+b.w); }
__device__ inline float4 f4sub(float4 a, float4 b) { return make_float4(a.x-b.x, a.y-b.y, a.z-b.z, a.w-b.w); }
__device__ inline float4 f4mul(float4 a, float4 b) { return make_float4(a.x*b.x, a.y*b.y, a.z*b.z, a.w*b.w); }

// 9-wide sliding sum along z: window = [L.x..L.w, M.x..M.w, R.x..R.w] (12 vals -> 4 outs)
__device__ inline float4 zbox9(float4 L, float4 M, float4 R) {
  float s8 = L.x+L.y+L.z+L.w + M.x+M.y+M.z+M.w;
  float o0 = s8 + R.x;
  float o1 = o0 + R.y - L.x;
  float o2 = o1 + R.z - L.y;
  float o3 = o2 + R.w - L.z;
  return make_float4(o0, o1, o2, o3);
}

__device__ inline float4 shfl4(float4 v, int src) {
  return make_float4(__shfl(v.x, src, 64), __shfl(v.y, src, 64),
                     __shfl(v.z, src, 64), __shfl(v.w, src, 64));
}

__global__ void ncc_init(double* acc) { *acc = 0.0; }

// Single LDS buffer Szx = Zbox(Xbox(5 products)) over [40 y-halo][32 z-out].
// Per x-step: ph3 (Y-box + NCC from Szx) ; barrier ; RMW Szx with
// zbox(slice x+5) - zbox(slice x-4) via lane-shuffled register z-box ; barrier.
__global__ __launch_bounds__(256) void ncc_fused(
    const float* __restrict__ I, const float* __restrict__ J,
    double* __restrict__ acc) {
  __shared__ float Szx[SZ_SZ];
  __shared__ double red[4];

  const int tid = threadIdx.x;
  const int xc0 = blockIdx.x * XCH;
  const int ty = blockIdx.y / 6, tz = blockIdx.y - 6 * (blockIdx.y / 6);
  const int b  = blockIdx.z;
  const int y0 = ty * TILE - PADW, z0 = tz * TILE - PADW;
  const float4* I4 = (const float4*)(I + (size_t)b * VOL);
  const float4* J4 = (const float4*)(J + (size_t)b * VOL);

  // ---- task geometry: rows of 10 z-quads, 6 rows per wave (lanes 60-63 idle)
  const int w = tid >> 6, l = tid & 63;
  const int lrow = l / 10, zf = l - 10 * lrow;
  const int sl = l ? l - 1 : 0, sr = (l < 63) ? l + 1 : 63;
  const int rowA = w * 6 + lrow;          // batch A: rows 0..23
  const int rowB = 24 + w * 6 + lrow;     // batch B: rows 24..39 (waves 0-2)
  const bool actA = (l < 60);
  const bool actB = (l < 60) && (rowB < TH);
  const int gz = z0 + 4 * zf;
  const bool zok = ((unsigned)gz < DIM);
  const int gyA = y0 + rowA, gyB = y0 + rowB;
  const bool ldA = actA && zok && ((unsigned)gyA < DIM);
  const bool ldB = actB && zok && ((unsigned)gyB < DIM);
  const bool prA = actA && zf >= 1 && zf <= 8 && ((unsigned)gyA < DIM);
  const bool prB = actB && zf >= 1 && zf <= 8 && ((unsigned)gyB < DIM);
  const int g4A = (gyA * DIM + gz) >> 2;  // only used under ldA
  const int g4B = (gyB * DIM + gz) >> 2;  // only used under ldB
  const int laA = rowA * SZP + 4 * (zf - 1);   // 16B-aligned
  const int laB = rowB * SZP + 4 * (zf - 1);

  for (int i = tid; i < SZ_SZ; i += 256) Szx[i] = 0.f;
  __syncthreads();

  const float4 z4 = make_float4(0.f, 0.f, 0.f, 0.f);

  // ---- prime: accumulate raw products over x in [xc0-4, xc0+4], zbox, store
  {
    float4 P1 = z4, P2 = z4, P3 = z4, P4 = z4, P5 = z4;
    if (ldA) {
      #pragma unroll
      for (int k = -PADW; k <= PADW; ++k) {
        int xx = xc0 + k;
        if ((unsigned)xx < DIM) {
          float4 a = I4[xx * YZ4 + g4A], c = J4[xx * YZ4 + g4A];
          P1 = f4add(P1, a); P2 = f4add(P2, c);
          P3 = f4add(P3, f4mul(a, a)); P4 = f4add(P4, f4mul(c, c)); P5 = f4add(P5, f4mul(a, c));
        }
      }
    }
    float4 L1 = shfl4(P1, sl), R1 = shfl4(P1, sr);
    float4 L2 = shfl4(P2, sl), R2 = shfl4(P2, sr);
    float4 L3 = shfl4(P3, sl), R3 = shfl4(P3, sr);
    float4 L4 = shfl4(P4, sl), R4 = shfl4(P4, sr);
    float4 L5 = shfl4(P5, sl), R5 = shfl4(P5, sr);
    if (prA) {
      *(float4*)(Szx + 0*SZ_CH + laA) = zbox9(L1, P1, R1);
      *(float4*)(Szx + 1*SZ_CH + laA) = zbox9(L2, P2, R2);
      *(float4*)(Szx + 2*SZ_CH + laA) = zbox9(L3, P3, R3);
      *(float4*)(Szx + 3*SZ_CH + laA) = zbox9(L4, P4, R4);
      *(float4*)(Szx + 4*SZ_CH + laA) = zbox9(L5, P5, R5);
    }
  }
  {
    float4 P1 = z4, P2 = z4, P3 = z4, P4 = z4, P5 = z4;
    if (ldB) {
      #pragma unroll
      for (int k = -PADW; k <= PADW; ++k) {
        int xx = xc0 + k;
        if ((unsigned)xx < DIM) {
          float4 a = I4[xx * YZ4 + g4B], c = J4[xx * YZ4 + g4B];
          P1 = f4add(P1, a); P2 = f4add(P2, c);
          P3 = f4add(P3, f4mul(a, a)); P4 = f4add(P4, f4mul(c, c)); P5 = f4add(P5, f4mul(a, c));
        }
      }
    }
    float4 L1 = shfl4(P1, sl), R1 = shfl4(P1, sr);
    float4 L2 = shfl4(P2, sl), R2 = shfl4(P2, sr);
    float4 L3 = shfl4(P3, sl), R3 = shfl4(P3, sr);
    float4 L4 = shfl4(P4, sl), R4 = shfl4(P4, sr);
    float4 L5 = shfl4(P5, sl), R5 = shfl4(P5, sr);
    if (prB) {
      *(float4*)(Szx + 0*SZ_CH + laB) = zbox9(L1, P1, R1);
      *(float4*)(Szx + 1*SZ_CH + laB) = zbox9(L2, P2, R2);
      *(float4*)(Szx + 2*SZ_CH + laB) = zbox9(L3, P3, R3);
      *(float4*)(Szx + 3*SZ_CH + laB) = zbox9(L4, P4, R4);
      *(float4*)(Szx + 4*SZ_CH + laB) = zbox9(L5, P5, R5);
    }
  }
  __syncthreads();

  double dsum = 0.0;
  const int zo = tid & 31, yb = (tid >> 5) * 4;
  const float inv = 1.0f / 729.0f;

  for (int xi = 0; xi < XCH; ++xi) {
    const int x = xc0 + xi;
    const bool hn = (xi + 1 < XCH);
    const int xa = x + PADW + 1, xs = x - PADW;
    const bool av = hn && (xa < DIM), sv = hn && (xs >= 0);

    // ---- issue next-transition loads early (hide under ph3)
    float4 nA0=z4,nC0=z4,oA0=z4,oC0=z4, nA1=z4,nC1=z4,oA1=z4,oC1=z4;
    if (ldA) {
      if (av) { nA0 = I4[xa * YZ4 + g4A]; nC0 = J4[xa * YZ4 + g4A]; }
      if (sv) { oA0 = I4[xs * YZ4 + g4A]; oC0 = J4[xs * YZ4 + g4A]; }
    }
    if (ldB) {
      if (av) { nA1 = I4[xa * YZ4 + g4B]; nC1 = J4[xa * YZ4 + g4B]; }
      if (sv) { oA1 = I4[xs * YZ4 + g4B]; oC1 = J4[xs * YZ4 + g4B]; }
    }

    // ---- ph3: Y-box + NCC from Szx (current x)
    {
      float sm[5][4];
      #pragma unroll
      for (int ch = 0; ch < 5; ++ch) {
        const float* col = Szx + ch * SZ_CH + zo;
        float v[12];
        #pragma unroll
        for (int k = 0; k < 12; ++k) v[k] = col[(yb + k) * SZP];
        float wsum = v[0]+v[1]+v[2]+v[3]+v[4]+v[5]+v[6]+v[7]+v[8];
        sm[ch][0] = wsum;
        #pragma unroll
        for (int r = 1; r < 4; ++r) { wsum += v[r+8]; wsum -= v[r-1]; sm[ch][r] = wsum; }
      }
      float part = 0.f;
      #pragma unroll
      for (int r = 0; r < 4; ++r) {
        float isv = sm[0][r], jsv = sm[1][r], i2 = sm[2][r], j2 = sm[3][r], ij = sm[4][r];
        float cross = ij - isv * jsv * inv;
        float ivr   = i2 - isv * isv * inv;
        float jvr   = j2 - jsv * jsv * inv;
        part += cross * cross / (ivr * jvr + 1e-5f);
      }
      dsum += (double)part;
    }
    __syncthreads();   // Szx reads done before RMW

    if (hn) {
      { // batch A: delta products -> shuffle neighbors -> zbox -> RMW
        float4 d1 = f4sub(nA0, oA0);
        float4 d2 = f4sub(nC0, oC0);
        float4 d3 = f4sub(f4mul(nA0, nA0), f4mul(oA0, oA0));
        float4 d4 = f4sub(f4mul(nC0, nC0), f4mul(oC0, oC0));
        float4 d5 = f4sub(f4mul(nA0, nC0), f4mul(oA0, oC0));
        float4 L1 = shfl4(d1, sl), R1 = shfl4(d1, sr);
        float4 L2 = shfl4(d2, sl), R2 = shfl4(d2, sr);
        float4 L3 = shfl4(d3, sl), R3 = shfl4(d3, sr);
        float4 L4 = shfl4(d4, sl), R4 = shfl4(d4, sr);
        float4 L5 = shfl4(d5, sl), R5 = shfl4(d5, sr);
        if (prA) {
          float4* p;
          p = (float4*)(Szx + 0*SZ_CH + laA); *p = f4add(*p, zbox9(L1, d1, R1));
          p = (float4*)(Szx + 1*SZ_CH + laA); *p = f4add(*p, zbox9(L2, d2, R2));
          p = (float4*)(Szx + 2*SZ_CH + laA); *p = f4add(*p, zbox9(L3, d3, R3));
          p = (float4*)(Szx + 3*SZ_CH + laA); *p = f4add(*p, zbox9(L4, d4, R4));
          p = (float4*)(Szx + 4*SZ_CH + laA); *p = f4add(*p, zbox9(L5, d5, R5));
        }
      }
      { // batch B
        float4 d1 = f4sub(nA1, oA1);
        float4 d2 = f4sub(nC1, oC1);
        float4 d3 = f4sub(f4mul(nA1, nA1), f4mul(oA1, oA1));
        float4 d4 = f4sub(f4mul(nC1, nC1), f4mul(oC1, oC1));
        float4 d5 = f4sub(f4mul(nA1, nC1), f4mul(oA1, oC1));
        float4 L1 = shfl4(d1, sl), R1 = shfl4(d1, sr);
        float4 L2 = shfl4(d2, sl), R2 = shfl4(d2, sr);
        float4 L3 = shfl4(d3, sl), R3 = shfl4(d3, sr);
        float4 L4 = shfl4(d4, sl), R4 = shfl4(d4, sr);
        float4 L5 = shfl4(d5, sl), R5 = shfl4(d5, sr);
        if (prB) {
          float4* p;
          p = (float4*)(Szx + 0*SZ_CH + laB); *p = f4add(*p, zbox9(L1, d1, R1));
          p = (float4*)(Szx + 1*SZ_CH + laB); *p = f4add(*p, zbox9(L2, d2, R2));
          p = (float4*)(Szx + 2*SZ_CH + laB); *p = f4add(*p, zbox9(L3, d3, R3));
          p = (float4*)(Szx + 3*SZ_CH + laB); *p = f4add(*p, zbox9(L4, d4, R4));
          p = (float4*)(Szx + 4*SZ_CH + laB); *p = f4add(*p, zbox9(L5, d5, R5));
        }
      }
      __syncthreads();   // RMW done before next ph3
    }
  }

  // ---- block reduction -> one atomic
  #pragma unroll
  for (int off = 32; off > 0; off >>= 1) dsum += __shfl_down(dsum, off, 64);
  if ((tid & 63) == 0) red[tid >> 6] = dsum;
  __syncthreads();
  if (tid == 0) atomicAdd(acc, red[0] + red[1] + red[2] + red[3]);
}

__global__ void ncc_fin(const double* __restrict__ acc, float* __restrict__ out) {
  out[0] = (float)(-(*acc) / (double)((size_t)NB * VOL));
}

extern "C" void kernel_launch(void* const* d_in, const int* in_sizes, int n_in,
                              void* d_out, int out_size, void* d_ws, size_t ws_size,
                              hipStream_t stream) {
  const float* I = (const float*)d_in[0];
  const float* J = (const float*)d_in[1];
  float* out = (float*)d_out;
  double* acc = (double*)d_ws;

  ncc_init<<<dim3(1), dim3(1), 0, stream>>>(acc);
  dim3 grid(NCHUNK, 36, NB);   // 16 x-chunks, 6x6 yz-tiles, 2 batch = 1152 blocks
  ncc_fused<<<grid, dim3(256), 0, stream>>>(I, J, acc);
  ncc_fin<<<dim3(1), dim3(1), 0, stream>>>(acc, out);
}